// Round 1
// baseline (1608.517 us; speedup 1.0000x reference)
//
#include <hip/hip_runtime.h>
#include <hip/hip_bf16.h>

#define T_TOKENS 8192
#define H_DIM 1024
#define F_DIM 4096
#define N_EXP 8
#define MAX_SLOTS 25600
#define MAX_TILES 200

typedef __attribute__((ext_vector_type(8))) short short8;
typedef __attribute__((ext_vector_type(4))) float floatx4;
typedef __attribute__((ext_vector_type(4))) int intx4;

__device__ __forceinline__ float gelu_f(float v) {
    return 0.5f * v * (1.0f + erff(v * 0.70710678118654752440f));
}

// ---------------- x -> bf16 ----------------
__global__ __launch_bounds__(256) void convert_x_kernel(const float* __restrict__ x,
                                                        unsigned long long* __restrict__ xb,
                                                        int n4) {
    int i = blockIdx.x * 256 + threadIdx.x;
    if (i >= n4) return;
    floatx4 v = ((const floatx4*)x)[i];
    union { __hip_bfloat16 h[4]; unsigned long long u; } p;
    p.h[0] = __float2bfloat16(v.x);
    p.h[1] = __float2bfloat16(v.y);
    p.h[2] = __float2bfloat16(v.z);
    p.h[3] = __float2bfloat16(v.w);
    xb[i] = p.u;
}

// ---------------- W [R][C] fp32 -> WT [C][R] bf16 (per blockIdx.z matrix) ----------------
__global__ __launch_bounds__(256) void transpose_convert_kernel(const float* __restrict__ in,
                                                                __hip_bfloat16* __restrict__ out,
                                                                int R, int C) {
    const float* inm = in + (size_t)blockIdx.z * R * C;
    __hip_bfloat16* outm = out + (size_t)blockIdx.z * R * C;
    __shared__ float tile[32][33];
    int r0 = blockIdx.x * 32;
    int c0 = blockIdx.y * 32;
    int tx = threadIdx.x & 31, ty = threadIdx.x >> 5;  // ty 0..7
#pragma unroll
    for (int i = 0; i < 4; i++)
        tile[ty + 8 * i][tx] = inm[(size_t)(r0 + ty + 8 * i) * C + c0 + tx];
    __syncthreads();
#pragma unroll
    for (int i = 0; i < 4; i++)
        outm[(size_t)(c0 + ty + 8 * i) * R + r0 + tx] = __float2bfloat16(tile[tx][ty + 8 * i]);
}

// ---------------- router: logits -> softmax -> top2 ----------------
__global__ __launch_bounds__(256) void router_kernel(const float* __restrict__ x,
                                                     const float* __restrict__ gw,
                                                     int* __restrict__ sel_e,
                                                     float* __restrict__ sel_w,
                                                     int* __restrict__ counts) {
    int wave = threadIdx.x >> 6, lane = threadIdx.x & 63;
    int t = blockIdx.x * 4 + wave;
    const float* xt = x + (size_t)t * H_DIM;
    float acc[N_EXP];
#pragma unroll
    for (int e = 0; e < N_EXP; e++) acc[e] = 0.f;
    for (int i = 0; i < H_DIM; i += 64) {
        float xv = xt[i + lane];
#pragma unroll
        for (int e = 0; e < N_EXP; e++) acc[e] += xv * gw[e * H_DIM + i + lane];
    }
#pragma unroll
    for (int e = 0; e < N_EXP; e++) {
#pragma unroll
        for (int off = 32; off > 0; off >>= 1) acc[e] += __shfl_down(acc[e], off);
    }
    if (lane == 0) {
        float m = acc[0];
#pragma unroll
        for (int e = 1; e < N_EXP; e++) m = fmaxf(m, acc[e]);
        float p[N_EXP];
#pragma unroll
        for (int e = 0; e < N_EXP; e++) p[e] = expf(acc[e] - m);
        int i1 = 0;
#pragma unroll
        for (int e = 1; e < N_EXP; e++) if (p[e] > p[i1]) i1 = e;
        int i2 = (i1 == 0) ? 1 : 0;
#pragma unroll
        for (int e = 0; e < N_EXP; e++) if (e != i1 && p[e] > p[i2]) i2 = e;
        float s = p[i1] + p[i2];
        sel_e[2 * t]     = i1;
        sel_e[2 * t + 1] = i2;
        sel_w[2 * t]     = p[i1] / s;
        sel_w[2 * t + 1] = p[i2] / s;
        atomicAdd(&counts[i1], 1);
        atomicAdd(&counts[i2], 1);
    }
}

// ---------------- offsets (128-aligned expert regions; region 8 = shared) ----------------
__global__ void offsets_kernel(const int* __restrict__ counts, int* __restrict__ off) {
    if (threadIdx.x == 0 && blockIdx.x == 0) {
        int o = 0;
#pragma unroll
        for (int e = 0; e < N_EXP; e++) {
            off[e] = o;
            o += ((counts[e] + 127) >> 7) << 7;
        }
        off[8] = o;
        off[9] = o + T_TOKENS;
    }
}

// ---------------- scatter tokens into slot arrays ----------------
__global__ __launch_bounds__(256) void scatter_kernel(const int* __restrict__ sel_e,
                                                      const float* __restrict__ sel_w,
                                                      const int* __restrict__ off,
                                                      int* __restrict__ pos,
                                                      int* __restrict__ slot_token,
                                                      float* __restrict__ slot_weight) {
    int t = blockIdx.x * 256 + threadIdx.x;
    if (t >= T_TOKENS) return;
#pragma unroll
    for (int k = 0; k < 2; k++) {
        int e = sel_e[2 * t + k];
        int p = atomicAdd(&pos[e], 1);
        int s = off[e] + p;
        slot_token[s] = t;
        slot_weight[s] = sel_w[2 * t + k];
    }
    int s = off[8] + t;
    slot_token[s] = t;
    slot_weight[s] = 1.0f;
}

// ---------------- GEMM1: h = gelu(x[slot] @ W1[e] + b1[e]) ----------------
// grid: (MAX_TILES, F/128). A gathered from xb via slot_token, B from pre-transposed w1t.
__global__ __launch_bounds__(256) void gemm1_kernel(const __hip_bfloat16* __restrict__ xb,
                                                    const __hip_bfloat16* __restrict__ w1t,
                                                    const __hip_bfloat16* __restrict__ sw1t,
                                                    const float* __restrict__ b1,
                                                    const float* __restrict__ sb1,
                                                    const int* __restrict__ slot_token,
                                                    const int* __restrict__ off,
                                                    __hip_bfloat16* __restrict__ h_buf) {
    int row0 = blockIdx.x * 128;
    if (row0 >= off[9]) return;
    int f0 = blockIdx.y * 128;
    int e = 8;
#pragma unroll
    for (int i = 0; i < 8; i++)
        if (row0 >= off[i] && row0 < off[i + 1]) e = i;
    const __hip_bfloat16* Bp = (e < 8) ? (w1t + (size_t)e * F_DIM * H_DIM) : sw1t;
    const float* bias = (e < 8) ? (b1 + (size_t)e * F_DIM) : sb1;

    __shared__ __align__(16) __hip_bfloat16 As[128 * 40];
    __shared__ __align__(16) __hip_bfloat16 Bs[128 * 40];

    int tid = threadIdx.x;
    int rA = tid >> 2, cc = tid & 3;
    int tok0 = slot_token[row0 + rA];
    int tok1 = slot_token[row0 + 64 + rA];
    const __hip_bfloat16* a0 = (tok0 >= 0) ? (xb + (size_t)tok0 * H_DIM) : (const __hip_bfloat16*)0;
    const __hip_bfloat16* a1 = (tok1 >= 0) ? (xb + (size_t)tok1 * H_DIM) : (const __hip_bfloat16*)0;
    const __hip_bfloat16* brow0 = Bp + (size_t)(f0 + rA) * H_DIM;
    const __hip_bfloat16* brow1 = Bp + (size_t)(f0 + 64 + rA) * H_DIM;

    int lane = tid & 63, wid = tid >> 6;
    int wm = (wid >> 1) * 64, wn = (wid & 1) * 64;
    int lr = lane & 15, q = lane >> 4;

    floatx4 acc[4][4] = {};

    for (int k0 = 0; k0 < H_DIM; k0 += 32) {
        intx4 z = {0, 0, 0, 0};
        intx4 va0 = a0 ? *(const intx4*)(a0 + k0 + cc * 8) : z;
        intx4 va1 = a1 ? *(const intx4*)(a1 + k0 + cc * 8) : z;
        intx4 vb0 = *(const intx4*)(brow0 + k0 + cc * 8);
        intx4 vb1 = *(const intx4*)(brow1 + k0 + cc * 8);
        *(intx4*)(&As[rA * 40 + cc * 8]) = va0;
        *(intx4*)(&As[(64 + rA) * 40 + cc * 8]) = va1;
        *(intx4*)(&Bs[rA * 40 + cc * 8]) = vb0;
        *(intx4*)(&Bs[(64 + rA) * 40 + cc * 8]) = vb1;
        __syncthreads();
        short8 af[4], bfr[4];
#pragma unroll
        for (int mt = 0; mt < 4; mt++) af[mt] = *(const short8*)(&As[(wm + mt * 16 + lr) * 40 + q * 8]);
#pragma unroll
        for (int nt = 0; nt < 4; nt++) bfr[nt] = *(const short8*)(&Bs[(wn + nt * 16 + lr) * 40 + q * 8]);
#pragma unroll
        for (int mt = 0; mt < 4; mt++)
#pragma unroll
            for (int nt = 0; nt < 4; nt++)
                acc[mt][nt] = __builtin_amdgcn_mfma_f32_16x16x32_bf16(af[mt], bfr[nt], acc[mt][nt], 0, 0, 0);
        __syncthreads();
    }

#pragma unroll
    for (int mt = 0; mt < 4; mt++) {
#pragma unroll
        for (int r = 0; r < 4; r++) {
            int row = wm + mt * 16 + q * 4 + r;
            int slot = row0 + row;
            int tok = slot_token[slot];
            __hip_bfloat16* hp = h_buf + (size_t)slot * F_DIM + f0;
#pragma unroll
            for (int nt = 0; nt < 4; nt++) {
                int col = wn + nt * 16 + lr;
                float v = acc[mt][nt][r] + bias[f0 + col];
                hp[col] = __float2bfloat16(tok >= 0 ? gelu_f(v) : 0.0f);
            }
        }
    }
}

// ---------------- GEMM2: out[tok] += w * (h[slot] @ W2[e] + b2[e]) ----------------
// grid: (H/128, MAX_TILES)
__global__ __launch_bounds__(256) void gemm2_kernel(const __hip_bfloat16* __restrict__ h_buf,
                                                    const __hip_bfloat16* __restrict__ w2t,
                                                    const __hip_bfloat16* __restrict__ sw2t,
                                                    const float* __restrict__ b2,
                                                    const float* __restrict__ sb2,
                                                    const int* __restrict__ slot_token,
                                                    const float* __restrict__ slot_weight,
                                                    const int* __restrict__ off,
                                                    float* __restrict__ out) {
    int row0 = blockIdx.y * 128;
    if (row0 >= off[9]) return;
    int h0 = blockIdx.x * 128;
    int e = 8;
#pragma unroll
    for (int i = 0; i < 8; i++)
        if (row0 >= off[i] && row0 < off[i + 1]) e = i;
    const __hip_bfloat16* Bp = (e < 8) ? (w2t + (size_t)e * H_DIM * F_DIM) : sw2t;
    const float* bias = (e < 8) ? (b2 + (size_t)e * H_DIM) : sb2;

    __shared__ __align__(16) __hip_bfloat16 As[128 * 40];
    __shared__ __align__(16) __hip_bfloat16 Bs[128 * 40];

    int tid = threadIdx.x;
    int rA = tid >> 2, cc = tid & 3;
    const __hip_bfloat16* a0 = h_buf + (size_t)(row0 + rA) * F_DIM;
    const __hip_bfloat16* a1 = h_buf + (size_t)(row0 + 64 + rA) * F_DIM;
    const __hip_bfloat16* brow0 = Bp + (size_t)(h0 + rA) * F_DIM;
    const __hip_bfloat16* brow1 = Bp + (size_t)(h0 + 64 + rA) * F_DIM;

    int lane = tid & 63, wid = tid >> 6;
    int wm = (wid >> 1) * 64, wn = (wid & 1) * 64;
    int lr = lane & 15, q = lane >> 4;

    floatx4 acc[4][4] = {};

    for (int k0 = 0; k0 < F_DIM; k0 += 32) {
        intx4 va0 = *(const intx4*)(a0 + k0 + cc * 8);
        intx4 va1 = *(const intx4*)(a1 + k0 + cc * 8);
        intx4 vb0 = *(const intx4*)(brow0 + k0 + cc * 8);
        intx4 vb1 = *(const intx4*)(brow1 + k0 + cc * 8);
        *(intx4*)(&As[rA * 40 + cc * 8]) = va0;
        *(intx4*)(&As[(64 + rA) * 40 + cc * 8]) = va1;
        *(intx4*)(&Bs[rA * 40 + cc * 8]) = vb0;
        *(intx4*)(&Bs[(64 + rA) * 40 + cc * 8]) = vb1;
        __syncthreads();
        short8 af[4], bfr[4];
#pragma unroll
        for (int mt = 0; mt < 4; mt++) af[mt] = *(const short8*)(&As[(wm + mt * 16 + lr) * 40 + q * 8]);
#pragma unroll
        for (int nt = 0; nt < 4; nt++) bfr[nt] = *(const short8*)(&Bs[(wn + nt * 16 + lr) * 40 + q * 8]);
#pragma unroll
        for (int mt = 0; mt < 4; mt++)
#pragma unroll
            for (int nt = 0; nt < 4; nt++)
                acc[mt][nt] = __builtin_amdgcn_mfma_f32_16x16x32_bf16(af[mt], bfr[nt], acc[mt][nt], 0, 0, 0);
        __syncthreads();
    }

#pragma unroll
    for (int mt = 0; mt < 4; mt++) {
#pragma unroll
        for (int r = 0; r < 4; r++) {
            int row = wm + mt * 16 + q * 4 + r;
            int slot = row0 + row;
            int tok = slot_token[slot];
            if (tok >= 0) {
                float w = slot_weight[slot];
                float* op = out + (size_t)tok * H_DIM + h0;
#pragma unroll
                for (int nt = 0; nt < 4; nt++) {
                    int col = wn + nt * 16 + lr;
                    atomicAdd(&op[col], w * (acc[mt][nt][r] + bias[h0 + col]));
                }
            }
        }
    }
}

extern "C" void kernel_launch(void* const* d_in, const int* in_sizes, int n_in,
                              void* d_out, int out_size, void* d_ws, size_t ws_size,
                              hipStream_t stream) {
    (void)in_sizes; (void)n_in; (void)ws_size;
    const float* x   = (const float*)d_in[0];
    const float* gw  = (const float*)d_in[1];
    const float* W1  = (const float*)d_in[2];
    const float* b1  = (const float*)d_in[3];
    const float* W2  = (const float*)d_in[4];
    const float* b2  = (const float*)d_in[5];
    const float* sW1 = (const float*)d_in[6];
    const float* sb1 = (const float*)d_in[7];
    const float* sW2 = (const float*)d_in[8];
    const float* sb2 = (const float*)d_in[9];
    float* out = (float*)d_out;

    char* ws = (char*)d_ws;
    size_t o = 0;
    auto alloc = [&](size_t bytes) -> void* {
        void* p = ws + o;
        o += (bytes + 255) & ~(size_t)255;
        return p;
    };
    __hip_bfloat16* xb    = (__hip_bfloat16*)alloc((size_t)T_TOKENS * H_DIM * 2);
    __hip_bfloat16* w1t   = (__hip_bfloat16*)alloc((size_t)N_EXP * H_DIM * F_DIM * 2);
    __hip_bfloat16* w2t   = (__hip_bfloat16*)alloc((size_t)N_EXP * H_DIM * F_DIM * 2);
    __hip_bfloat16* sw1t  = (__hip_bfloat16*)alloc((size_t)H_DIM * F_DIM * 2);
    __hip_bfloat16* sw2t  = (__hip_bfloat16*)alloc((size_t)H_DIM * F_DIM * 2);
    __hip_bfloat16* h_buf = (__hip_bfloat16*)alloc((size_t)MAX_SLOTS * F_DIM * 2);
    int*   slot_token  = (int*)alloc(MAX_SLOTS * 4);
    float* slot_weight = (float*)alloc(MAX_SLOTS * 4);
    int*   sel_e = (int*)alloc((size_t)T_TOKENS * 2 * 4);
    float* sel_w = (float*)alloc((size_t)T_TOKENS * 2 * 4);
    int*   ctrl  = (int*)alloc(64 * 4);  // counts[8] | pos[8] | off[16]
    int* counts = ctrl;
    int* pos    = ctrl + 8;
    int* off    = ctrl + 16;

    hipMemsetAsync(d_out, 0, (size_t)out_size * sizeof(float), stream);
    hipMemsetAsync(ctrl, 0, 64 * 4, stream);
    hipMemsetAsync(slot_token, 0xFF, MAX_SLOTS * 4, stream);

    int n4 = T_TOKENS * H_DIM / 4;
    convert_x_kernel<<<(n4 + 255) / 256, 256, 0, stream>>>(x, (unsigned long long*)xb, n4);

    transpose_convert_kernel<<<dim3(H_DIM / 32, F_DIM / 32, N_EXP), 256, 0, stream>>>(W1, w1t, H_DIM, F_DIM);
    transpose_convert_kernel<<<dim3(F_DIM / 32, H_DIM / 32, N_EXP), 256, 0, stream>>>(W2, w2t, F_DIM, H_DIM);
    transpose_convert_kernel<<<dim3(H_DIM / 32, F_DIM / 32, 1), 256, 0, stream>>>(sW1, sw1t, H_DIM, F_DIM);
    transpose_convert_kernel<<<dim3(F_DIM / 32, H_DIM / 32, 1), 256, 0, stream>>>(sW2, sw2t, F_DIM, H_DIM);

    router_kernel<<<T_TOKENS / 4, 256, 0, stream>>>(x, gw, sel_e, sel_w, counts);
    offsets_kernel<<<1, 64, 0, stream>>>(counts, off);
    scatter_kernel<<<T_TOKENS / 256, 256, 0, stream>>>(sel_e, sel_w, off, pos, slot_token, slot_weight);

    gemm1_kernel<<<dim3(MAX_TILES, F_DIM / 128), 256, 0, stream>>>(
        xb, w1t, sw1t, b1, sb1, slot_token, off, h_buf);
    gemm2_kernel<<<dim3(H_DIM / 128, MAX_TILES), 256, 0, stream>>>(
        h_buf, w2t, sw2t, b2, sb2, slot_token, slot_weight, off, out);
}

// Round 2
// 1558.136 us; speedup vs baseline: 1.0323x; 1.0323x over previous
//
#include <hip/hip_runtime.h>
#include <hip/hip_bf16.h>

#define T_TOKENS 8192
#define H_DIM 1024
#define F_DIM 4096
#define N_EXP 8
#define MAX_SLOTS 25600
#define MAX_TILES 200

typedef __attribute__((ext_vector_type(8))) short short8;
typedef __attribute__((ext_vector_type(4))) float floatx4;

__device__ __forceinline__ float gelu_f(float v) {
    return 0.5f * v * (1.0f + erff(v * 0.70710678118654752440f));
}

// async global->LDS, 16B per lane; LDS dest = wave-uniform base + lane*16
__device__ __forceinline__ void gload_lds16(const void* g, void* l) {
    __builtin_amdgcn_global_load_lds((const __attribute__((address_space(1))) void*)g,
                                     (__attribute__((address_space(3))) void*)l,
                                     16, 0, 0);
}

// ---------------- x -> bf16 ----------------
__global__ __launch_bounds__(256) void convert_x_kernel(const float* __restrict__ x,
                                                        unsigned long long* __restrict__ xb,
                                                        int n4) {
    int i = blockIdx.x * 256 + threadIdx.x;
    if (i >= n4) return;
    floatx4 v = ((const floatx4*)x)[i];
    union { __hip_bfloat16 h[4]; unsigned long long u; } p;
    p.h[0] = __float2bfloat16(v.x);
    p.h[1] = __float2bfloat16(v.y);
    p.h[2] = __float2bfloat16(v.z);
    p.h[3] = __float2bfloat16(v.w);
    xb[i] = p.u;
}

// ---------------- W [R][C] fp32 -> WT [C][R] bf16 (per blockIdx.z matrix) ----------------
__global__ __launch_bounds__(256) void transpose_convert_kernel(const float* __restrict__ in,
                                                                __hip_bfloat16* __restrict__ out,
                                                                int R, int C) {
    const float* inm = in + (size_t)blockIdx.z * R * C;
    __hip_bfloat16* outm = out + (size_t)blockIdx.z * R * C;
    __shared__ float tile[32][33];
    int r0 = blockIdx.x * 32;
    int c0 = blockIdx.y * 32;
    int tx = threadIdx.x & 31, ty = threadIdx.x >> 5;  // ty 0..7
#pragma unroll
    for (int i = 0; i < 4; i++)
        tile[ty + 8 * i][tx] = inm[(size_t)(r0 + ty + 8 * i) * C + c0 + tx];
    __syncthreads();
#pragma unroll
    for (int i = 0; i < 4; i++)
        outm[(size_t)(c0 + ty + 8 * i) * R + r0 + tx] = __float2bfloat16(tile[tx][ty + 8 * i]);
}

// ---------------- router: logits -> softmax -> top2 ----------------
__global__ __launch_bounds__(256) void router_kernel(const float* __restrict__ x,
                                                     const float* __restrict__ gw,
                                                     int* __restrict__ sel_e,
                                                     float* __restrict__ sel_w,
                                                     int* __restrict__ counts) {
    int wave = threadIdx.x >> 6, lane = threadIdx.x & 63;
    int t = blockIdx.x * 4 + wave;
    const float* xt = x + (size_t)t * H_DIM;
    float acc[N_EXP];
#pragma unroll
    for (int e = 0; e < N_EXP; e++) acc[e] = 0.f;
    for (int i = 0; i < H_DIM; i += 64) {
        float xv = xt[i + lane];
#pragma unroll
        for (int e = 0; e < N_EXP; e++) acc[e] += xv * gw[e * H_DIM + i + lane];
    }
#pragma unroll
    for (int e = 0; e < N_EXP; e++) {
#pragma unroll
        for (int off = 32; off > 0; off >>= 1) acc[e] += __shfl_down(acc[e], off);
    }
    if (lane == 0) {
        float m = acc[0];
#pragma unroll
        for (int e = 1; e < N_EXP; e++) m = fmaxf(m, acc[e]);
        float p[N_EXP];
#pragma unroll
        for (int e = 0; e < N_EXP; e++) p[e] = expf(acc[e] - m);
        int i1 = 0;
#pragma unroll
        for (int e = 1; e < N_EXP; e++) if (p[e] > p[i1]) i1 = e;
        int i2 = (i1 == 0) ? 1 : 0;
#pragma unroll
        for (int e = 0; e < N_EXP; e++) if (e != i1 && p[e] > p[i2]) i2 = e;
        float s = p[i1] + p[i2];
        sel_e[2 * t]     = i1;
        sel_e[2 * t + 1] = i2;
        sel_w[2 * t]     = p[i1] / s;
        sel_w[2 * t + 1] = p[i2] / s;
        atomicAdd(&counts[i1], 1);
        atomicAdd(&counts[i2], 1);
    }
}

// ---------------- offsets (128-aligned expert regions; region 8 = shared) ----------------
__global__ void offsets_kernel(const int* __restrict__ counts, int* __restrict__ off) {
    if (threadIdx.x == 0 && blockIdx.x == 0) {
        int o = 0;
#pragma unroll
        for (int e = 0; e < N_EXP; e++) {
            off[e] = o;
            o += ((counts[e] + 127) >> 7) << 7;
        }
        off[8] = o;
        off[9] = o + T_TOKENS;
    }
}

// ---------------- scatter tokens into slot arrays ----------------
__global__ __launch_bounds__(256) void scatter_kernel(const int* __restrict__ sel_e,
                                                      const float* __restrict__ sel_w,
                                                      const int* __restrict__ off,
                                                      int* __restrict__ pos,
                                                      int* __restrict__ slot_token,
                                                      float* __restrict__ slot_weight) {
    int t = blockIdx.x * 256 + threadIdx.x;
    if (t >= T_TOKENS) return;
#pragma unroll
    for (int k = 0; k < 2; k++) {
        int e = sel_e[2 * t + k];
        int p = atomicAdd(&pos[e], 1);
        int s = off[e] + p;
        slot_token[s] = t;
        slot_weight[s] = sel_w[2 * t + k];
    }
    int s = off[8] + t;
    slot_token[s] = t;
    slot_weight[s] = 1.0f;
}

// ---------------- GEMM1: h = gelu(x[slot] @ W1[e] + b1[e]) ----------------
// grid: (MAX_TILES, F/128). m97 structure: global_load_lds(16B) staging,
// unpadded LDS tiles (row stride 64B), ds_read_b128 fragments.
__global__ __launch_bounds__(256) void gemm1_kernel(const __hip_bfloat16* __restrict__ xb,
                                                    const __hip_bfloat16* __restrict__ w1t,
                                                    const __hip_bfloat16* __restrict__ sw1t,
                                                    const float* __restrict__ b1,
                                                    const float* __restrict__ sb1,
                                                    const int* __restrict__ slot_token,
                                                    const int* __restrict__ off,
                                                    __hip_bfloat16* __restrict__ h_buf) {
    int row0 = blockIdx.x * 128;
    if (row0 >= off[9]) return;
    int f0 = blockIdx.y * 128;
    int e = 8;
#pragma unroll
    for (int i = 0; i < 8; i++)
        if (row0 >= off[i] && row0 < off[i + 1]) e = i;
    const __hip_bfloat16* Bp = (e < 8) ? (w1t + (size_t)e * F_DIM * H_DIM) : sw1t;
    const float* bias = (e < 8) ? (b1 + (size_t)e * F_DIM) : sb1;

    __shared__ __align__(16) __hip_bfloat16 As[128 * 32];
    __shared__ __align__(16) __hip_bfloat16 Bs[128 * 32];

    int tid = threadIdx.x;
    int rA = tid >> 2, cc = tid & 3;
    int tok0 = slot_token[row0 + rA];
    int tok1 = slot_token[row0 + 64 + rA];
    int t0c = tok0 >= 0 ? tok0 : 0;  // clamp pads to a valid row; epilogue zeroes them
    int t1c = tok1 >= 0 ? tok1 : 0;
    const __hip_bfloat16* a0 = xb + (size_t)t0c * H_DIM + cc * 8;
    const __hip_bfloat16* a1 = xb + (size_t)t1c * H_DIM + cc * 8;
    const __hip_bfloat16* b0 = Bp + (size_t)(f0 + rA) * H_DIM + cc * 8;
    const __hip_bfloat16* b1r = Bp + (size_t)(f0 + 64 + rA) * H_DIM + cc * 8;

    int lane = tid & 63, wid = tid >> 6;
    // wave-uniform LDS staging bases (lane*16 added by HW)
    char* asb0 = (char*)As + wid * 1024;
    char* asb1 = (char*)As + 4096 + wid * 1024;
    char* bsb0 = (char*)Bs + wid * 1024;
    char* bsb1 = (char*)Bs + 4096 + wid * 1024;

    int wm = (wid >> 1) * 64, wn = (wid & 1) * 64;
    int lr = lane & 15, q = lane >> 4;

    floatx4 acc[4][4] = {};

    for (int k0 = 0; k0 < H_DIM; k0 += 32) {
        gload_lds16(a0 + k0, asb0);
        gload_lds16(a1 + k0, asb1);
        gload_lds16(b0 + k0, bsb0);
        gload_lds16(b1r + k0, bsb1);
        __syncthreads();
        short8 af[4], bfr[4];
#pragma unroll
        for (int mt = 0; mt < 4; mt++) af[mt] = *(const short8*)(&As[(wm + mt * 16 + lr) * 32 + q * 8]);
#pragma unroll
        for (int nt = 0; nt < 4; nt++) bfr[nt] = *(const short8*)(&Bs[(wn + nt * 16 + lr) * 32 + q * 8]);
#pragma unroll
        for (int mt = 0; mt < 4; mt++)
#pragma unroll
            for (int nt = 0; nt < 4; nt++)
                acc[mt][nt] = __builtin_amdgcn_mfma_f32_16x16x32_bf16(af[mt], bfr[nt], acc[mt][nt], 0, 0, 0);
        __syncthreads();
    }

#pragma unroll
    for (int mt = 0; mt < 4; mt++) {
#pragma unroll
        for (int r = 0; r < 4; r++) {
            int row = wm + mt * 16 + q * 4 + r;
            int slot = row0 + row;
            int tok = slot_token[slot];
            __hip_bfloat16* hp = h_buf + (size_t)slot * F_DIM + f0;
#pragma unroll
            for (int nt = 0; nt < 4; nt++) {
                int col = wn + nt * 16 + lr;
                float v = acc[mt][nt][r] + bias[f0 + col];
                hp[col] = __float2bfloat16(tok >= 0 ? gelu_f(v) : 0.0f);
            }
        }
    }
}

// ---------------- GEMM2: out[tok] += w * (h[slot] @ W2[e] + b2[e]) ----------------
// grid: (H/128, MAX_TILES)
__global__ __launch_bounds__(256) void gemm2_kernel(const __hip_bfloat16* __restrict__ h_buf,
                                                    const __hip_bfloat16* __restrict__ w2t,
                                                    const __hip_bfloat16* __restrict__ sw2t,
                                                    const float* __restrict__ b2,
                                                    const float* __restrict__ sb2,
                                                    const int* __restrict__ slot_token,
                                                    const float* __restrict__ slot_weight,
                                                    const int* __restrict__ off,
                                                    float* __restrict__ out) {
    int row0 = blockIdx.y * 128;
    if (row0 >= off[9]) return;
    int h0 = blockIdx.x * 128;
    int e = 8;
#pragma unroll
    for (int i = 0; i < 8; i++)
        if (row0 >= off[i] && row0 < off[i + 1]) e = i;
    const __hip_bfloat16* Bp = (e < 8) ? (w2t + (size_t)e * H_DIM * F_DIM) : sw2t;
    const float* bias = (e < 8) ? (b2 + (size_t)e * H_DIM) : sb2;

    __shared__ __align__(16) __hip_bfloat16 As[128 * 32];
    __shared__ __align__(16) __hip_bfloat16 Bs[128 * 32];

    int tid = threadIdx.x;
    int rA = tid >> 2, cc = tid & 3;
    const __hip_bfloat16* a0 = h_buf + (size_t)(row0 + rA) * F_DIM + cc * 8;
    const __hip_bfloat16* a1 = h_buf + (size_t)(row0 + 64 + rA) * F_DIM + cc * 8;
    const __hip_bfloat16* b0 = Bp + (size_t)(h0 + rA) * F_DIM + cc * 8;
    const __hip_bfloat16* b1r = Bp + (size_t)(h0 + 64 + rA) * F_DIM + cc * 8;

    int lane = tid & 63, wid = tid >> 6;
    char* asb0 = (char*)As + wid * 1024;
    char* asb1 = (char*)As + 4096 + wid * 1024;
    char* bsb0 = (char*)Bs + wid * 1024;
    char* bsb1 = (char*)Bs + 4096 + wid * 1024;

    int wm = (wid >> 1) * 64, wn = (wid & 1) * 64;
    int lr = lane & 15, q = lane >> 4;

    floatx4 acc[4][4] = {};

    for (int k0 = 0; k0 < F_DIM; k0 += 32) {
        gload_lds16(a0 + k0, asb0);
        gload_lds16(a1 + k0, asb1);
        gload_lds16(b0 + k0, bsb0);
        gload_lds16(b1r + k0, bsb1);
        __syncthreads();
        short8 af[4], bfr[4];
#pragma unroll
        for (int mt = 0; mt < 4; mt++) af[mt] = *(const short8*)(&As[(wm + mt * 16 + lr) * 32 + q * 8]);
#pragma unroll
        for (int nt = 0; nt < 4; nt++) bfr[nt] = *(const short8*)(&Bs[(wn + nt * 16 + lr) * 32 + q * 8]);
#pragma unroll
        for (int mt = 0; mt < 4; mt++)
#pragma unroll
            for (int nt = 0; nt < 4; nt++)
                acc[mt][nt] = __builtin_amdgcn_mfma_f32_16x16x32_bf16(af[mt], bfr[nt], acc[mt][nt], 0, 0, 0);
        __syncthreads();
    }

#pragma unroll
    for (int mt = 0; mt < 4; mt++) {
#pragma unroll
        for (int r = 0; r < 4; r++) {
            int row = wm + mt * 16 + q * 4 + r;
            int slot = row0 + row;
            int tok = slot_token[slot];
            if (tok >= 0) {
                float w = slot_weight[slot];
                float* op = out + (size_t)tok * H_DIM + h0;
#pragma unroll
                for (int nt = 0; nt < 4; nt++) {
                    int col = wn + nt * 16 + lr;
                    atomicAdd(&op[col], w * (acc[mt][nt][r] + bias[h0 + col]));
                }
            }
        }
    }
}

extern "C" void kernel_launch(void* const* d_in, const int* in_sizes, int n_in,
                              void* d_out, int out_size, void* d_ws, size_t ws_size,
                              hipStream_t stream) {
    (void)in_sizes; (void)n_in; (void)ws_size;
    const float* x   = (const float*)d_in[0];
    const float* gw  = (const float*)d_in[1];
    const float* W1  = (const float*)d_in[2];
    const float* b1  = (const float*)d_in[3];
    const float* W2  = (const float*)d_in[4];
    const float* b2  = (const float*)d_in[5];
    const float* sW1 = (const float*)d_in[6];
    const float* sb1 = (const float*)d_in[7];
    const float* sW2 = (const float*)d_in[8];
    const float* sb2 = (const float*)d_in[9];
    float* out = (float*)d_out;

    char* ws = (char*)d_ws;
    size_t o = 0;
    auto alloc = [&](size_t bytes) -> void* {
        void* p = ws + o;
        o += (bytes + 255) & ~(size_t)255;
        return p;
    };
    __hip_bfloat16* xb    = (__hip_bfloat16*)alloc((size_t)T_TOKENS * H_DIM * 2);
    __hip_bfloat16* w1t   = (__hip_bfloat16*)alloc((size_t)N_EXP * H_DIM * F_DIM * 2);
    __hip_bfloat16* w2t   = (__hip_bfloat16*)alloc((size_t)N_EXP * H_DIM * F_DIM * 2);
    __hip_bfloat16* sw1t  = (__hip_bfloat16*)alloc((size_t)H_DIM * F_DIM * 2);
    __hip_bfloat16* sw2t  = (__hip_bfloat16*)alloc((size_t)H_DIM * F_DIM * 2);
    __hip_bfloat16* h_buf = (__hip_bfloat16*)alloc((size_t)MAX_SLOTS * F_DIM * 2);
    int*   slot_token  = (int*)alloc(MAX_SLOTS * 4);
    float* slot_weight = (float*)alloc(MAX_SLOTS * 4);
    int*   sel_e = (int*)alloc((size_t)T_TOKENS * 2 * 4);
    float* sel_w = (float*)alloc((size_t)T_TOKENS * 2 * 4);
    int*   ctrl  = (int*)alloc(64 * 4);  // counts[8] | pos[8] | off[16]
    int* counts = ctrl;
    int* pos    = ctrl + 8;
    int* off    = ctrl + 16;

    hipMemsetAsync(d_out, 0, (size_t)out_size * sizeof(float), stream);
    hipMemsetAsync(ctrl, 0, 64 * 4, stream);
    hipMemsetAsync(slot_token, 0xFF, MAX_SLOTS * 4, stream);

    int n4 = T_TOKENS * H_DIM / 4;
    convert_x_kernel<<<(n4 + 255) / 256, 256, 0, stream>>>(x, (unsigned long long*)xb, n4);

    transpose_convert_kernel<<<dim3(H_DIM / 32, F_DIM / 32, N_EXP), 256, 0, stream>>>(W1, w1t, H_DIM, F_DIM);
    transpose_convert_kernel<<<dim3(F_DIM / 32, H_DIM / 32, N_EXP), 256, 0, stream>>>(W2, w2t, F_DIM, H_DIM);
    transpose_convert_kernel<<<dim3(H_DIM / 32, F_DIM / 32, 1), 256, 0, stream>>>(sW1, sw1t, H_DIM, F_DIM);
    transpose_convert_kernel<<<dim3(F_DIM / 32, H_DIM / 32, 1), 256, 0, stream>>>(sW2, sw2t, F_DIM, H_DIM);

    router_kernel<<<T_TOKENS / 4, 256, 0, stream>>>(x, gw, sel_e, sel_w, counts);
    offsets_kernel<<<1, 64, 0, stream>>>(counts, off);
    scatter_kernel<<<T_TOKENS / 256, 256, 0, stream>>>(sel_e, sel_w, off, pos, slot_token, slot_weight);

    gemm1_kernel<<<dim3(MAX_TILES, F_DIM / 128), 256, 0, stream>>>(
        xb, w1t, sw1t, b1, sb1, slot_token, off, h_buf);
    gemm2_kernel<<<dim3(H_DIM / 128, MAX_TILES), 256, 0, stream>>>(
        h_buf, w2t, sw2t, b2, sb2, slot_token, slot_weight, off, out);
}